// Round 1
// baseline (1213.534 us; speedup 1.0000x reference)
//
#include <hip/hip_runtime.h>

#define DFEAT 64
#define EPS 1e-12f

// ---------------------------------------------------------------------------
// R8: exact global CSR build (hist -> scan -> place) + LDS-free CSR gather.
// R7 post-mortem: bucket_sort_gather was latency-bound (occ 40%, HBM 34%,
// VALU 38%) -- 30KB lsort LDS capped residency at ~4 blocks/CU and 3 LDS
// passes over all 8M records preceded the real gather. Partition paid two
// scattered sub-word stores per record. CSR placement stores each record
// once at its final bin-sorted position (bin encoded by position, binlo
// array eliminated); gather has zero LDS -> wave-slot-limited occupancy.
// Arithmetic identical to R7 (same w packing) -> absmax unchanged.
// ---------------------------------------------------------------------------

__device__ __forceinline__ unsigned pack_src_w(int s, float w) {
    // w uniform [0,1): keep 15 bits (sign-free bf16), round-to-nearest.
    unsigned u = __float_as_uint(w) + 0x8000u;
    return (((u >> 16) & 0x7FFFu) << 17) | (unsigned)s;   // src < 2^17
}
__device__ __forceinline__ int unpack_src(unsigned p) { return (int)(p & 0x1FFFFu); }
__device__ __forceinline__ float unpack_w(unsigned p) {
    return __uint_as_float(((p >> 17) & 0x7FFFu) << 16);
}

__global__ void zero_int_kernel(int* __restrict__ p, int n) {
    int i = blockIdx.x * blockDim.x + threadIdx.x;
    if (i < n) p[i] = 0;
}

// ---- CSR step 1: per-bin histogram (global atomics, ~40-way mean contention)
__global__ void hist_kernel(const int* __restrict__ dst_ui,
                            const int* __restrict__ dst_iu,
                            int* __restrict__ cnt, int n_edges, int n_nodes) {
    long long g = (long long)blockIdx.x * blockDim.x + threadIdx.x;
    long long total = 2LL * n_edges;
    if (g >= total) return;
    int bin = (g < n_edges) ? dst_ui[g] : n_nodes + dst_iu[g - n_edges];
    atomicAdd(&cnt[bin], 1);
}

// ---- CSR step 2a: per-256-bin chunk sums
__global__ void chunk_sum_kernel(const int* __restrict__ cnt,
                                 int* __restrict__ chunksum, int n_bins) {
    __shared__ int wt[4];
    int tid = threadIdx.x;
    int i = blockIdx.x * 256 + tid;
    int v = (i < n_bins) ? cnt[i] : 0;
    #pragma unroll
    for (int o = 32; o > 0; o >>= 1) v += __shfl_xor(v, o, 64);
    if ((tid & 63) == 0) wt[tid >> 6] = v;
    __syncthreads();
    if (tid == 0) chunksum[blockIdx.x] = wt[0] + wt[1] + wt[2] + wt[3];
}

// ---- CSR step 2b: single-block exclusive scan of chunk sums (nchunks <= 1024)
__global__ void chunk_scan_kernel(const int* __restrict__ chunksum,
                                  int* __restrict__ chunkoff, int nchunks) {
    __shared__ int s[1024];
    int tid = threadIdx.x;
    s[tid] = (tid < nchunks) ? chunksum[tid] : 0;
    __syncthreads();
    for (int off = 1; off < 1024; off <<= 1) {
        int v = (tid >= off) ? s[tid - off] : 0;
        __syncthreads();
        s[tid] += v;
        __syncthreads();
    }
    if (tid < nchunks) chunkoff[tid] = (tid == 0) ? 0 : s[tid - 1];
    if (tid == 0) chunkoff[nchunks] = s[nchunks - 1];
}

// ---- CSR step 2c: final rowptr (exclusive) + working cursor copy
__global__ void rowptr_kernel(const int* __restrict__ cnt,
                              const int* __restrict__ chunkoff,
                              int* __restrict__ rowptr,
                              int* __restrict__ cursor, int n_bins) {
    __shared__ int wt[4];
    int tid = threadIdx.x;
    int lane = tid & 63;
    int wid = tid >> 6;
    int i = blockIdx.x * 256 + tid;
    int v = (i < n_bins) ? cnt[i] : 0;
    int sc = v;
    #pragma unroll
    for (int o = 1; o < 64; o <<= 1) {
        int y = __shfl_up(sc, o, 64);
        if (lane >= o) sc += y;
    }
    if (lane == 63) wt[wid] = sc;
    __syncthreads();
    int add = chunkoff[blockIdx.x];
    for (int w = 0; w < wid; ++w) add += wt[w];
    int incl = sc + add;
    int excl = incl - v;
    if (i < n_bins) { rowptr[i] = excl; cursor[i] = excl; }
    if (i == n_bins - 1) rowptr[n_bins] = incl;   // grand total
}

// ---- CSR step 3: place each record at its final bin-sorted slot.
// One returning atomic + ONE scattered 4B store per record (binlo gone).
__global__ void place_kernel(const int* __restrict__ src_ui,
                             const int* __restrict__ dst_ui,
                             const float* __restrict__ norm_ui,
                             const int* __restrict__ src_iu,
                             const int* __restrict__ dst_iu,
                             const float* __restrict__ norm_iu,
                             int* __restrict__ cursor,
                             unsigned* __restrict__ srcw,
                             int n_edges, int n_nodes) {
    long long g = (long long)blockIdx.x * blockDim.x + threadIdx.x;
    long long total = 2LL * n_edges;
    if (g >= total) return;
    int bin, s; float w;
    if (g < n_edges) {
        bin = dst_ui[g]; s = src_ui[g]; w = norm_ui[g];
    } else {
        long long e = g - n_edges;
        bin = n_nodes + dst_iu[e]; s = src_iu[e]; w = norm_iu[e];
    }
    int pos = atomicAdd(&cursor[bin], 1);
    srcw[pos] = pack_src_w(s, w);
}

// ---- CSR gather: one output row per wave, zero LDS, register accumulate,
// fused L2-normalize + coalesced store. 8 independent 256B row loads in
// flight per wave; occupancy limited only by wave slots / VGPRs.
__global__ __launch_bounds__(256, 8) void csr_gather_kernel(
    const float* __restrict__ user_feat,
    const float* __restrict__ item_feat,
    const int* __restrict__ rowptr,
    const unsigned* __restrict__ srcw,
    float* __restrict__ out, int n_nodes) {
    const int tid = threadIdx.x;
    const int lane = tid & 63;
    const int wid = tid >> 6;
    const int n_bins = 2 * n_nodes;
    const int r = blockIdx.x * 4 + wid;
    if (r >= n_bins) return;
    const float* feat = (r < n_nodes) ? user_feat : item_feat;
    const int js = rowptr[r];
    const int je = rowptr[r + 1];
    float acc = 0.f;
    int j = js;
    for (; j + 8 <= je; j += 8) {
        unsigned s0 = srcw[j + 0];
        unsigned s1 = srcw[j + 1];
        unsigned s2 = srcw[j + 2];
        unsigned s3 = srcw[j + 3];
        unsigned s4 = srcw[j + 4];
        unsigned s5 = srcw[j + 5];
        unsigned s6 = srcw[j + 6];
        unsigned s7 = srcw[j + 7];
        float f0 = feat[(long long)unpack_src(s0) * DFEAT + lane];
        float f1 = feat[(long long)unpack_src(s1) * DFEAT + lane];
        float f2 = feat[(long long)unpack_src(s2) * DFEAT + lane];
        float f3 = feat[(long long)unpack_src(s3) * DFEAT + lane];
        float f4 = feat[(long long)unpack_src(s4) * DFEAT + lane];
        float f5 = feat[(long long)unpack_src(s5) * DFEAT + lane];
        float f6 = feat[(long long)unpack_src(s6) * DFEAT + lane];
        float f7 = feat[(long long)unpack_src(s7) * DFEAT + lane];
        acc += unpack_w(s0) * f0;
        acc += unpack_w(s1) * f1;
        acc += unpack_w(s2) * f2;
        acc += unpack_w(s3) * f3;
        acc += unpack_w(s4) * f4;
        acc += unpack_w(s5) * f5;
        acc += unpack_w(s6) * f6;
        acc += unpack_w(s7) * f7;
    }
    for (; j < je; ++j) {
        unsigned s = srcw[j];
        acc += unpack_w(s) * feat[(long long)unpack_src(s) * DFEAT + lane];
    }
    float ss = acc * acc;
    #pragma unroll
    for (int o = 32; o > 0; o >>= 1) ss += __shfl_xor(ss, o, 64);
    float scale = 1.0f / fmaxf(sqrtf(ss), EPS);
    // out rows [0,N) = user_h <- bins [N,2N); rows [N,2N) = item_h <- bins [0,N)
    int out_row = (r < n_nodes) ? (r + n_nodes) : (r - n_nodes);
    out[(long long)out_row * DFEAT + lane] = acc * scale;
}

// ---------------------------------------------------------------------------
// Fallback atomic path (proven in R3) if ws_size / shape limits are exceeded.
// ---------------------------------------------------------------------------

__global__ void zero_f32_kernel(float* __restrict__ p, int n4) {
    int i = blockIdx.x * blockDim.x + threadIdx.x;
    if (i < n4) reinterpret_cast<float4*>(p)[i] = make_float4(0.f, 0.f, 0.f, 0.f);
}

__global__ void scatter_edges_kernel(const float* __restrict__ user_feat,
                                     const float* __restrict__ item_feat,
                                     const float* __restrict__ norm_ui,
                                     const float* __restrict__ norm_iu,
                                     const int* __restrict__ src_ui,
                                     const int* __restrict__ dst_ui,
                                     const int* __restrict__ src_iu,
                                     const int* __restrict__ dst_iu,
                                     float* __restrict__ user_acc,
                                     float* __restrict__ item_acc,
                                     int n_edges) {
    long long idx = (long long)blockIdx.x * blockDim.x + threadIdx.x;
    int e = (int)(idx >> 6);
    int d = (int)(idx & 63);
    if (e < n_edges) {
        int s = src_ui[e];
        int t = dst_ui[e];
        atomicAdd(&item_acc[(long long)t * DFEAT + d],
                  norm_ui[e] * user_feat[(long long)s * DFEAT + d]);
    } else {
        e -= n_edges;
        if (e < n_edges) {
            int s = src_iu[e];
            int t = dst_iu[e];
            atomicAdd(&user_acc[(long long)t * DFEAT + d],
                      norm_iu[e] * item_feat[(long long)s * DFEAT + d]);
        }
    }
}

__global__ void normalize_rows_kernel(float* __restrict__ buf, int n_rows) {
    int gid = blockIdx.x * blockDim.x + threadIdx.x;
    int row = gid >> 6;
    int lane = gid & 63;
    if (row >= n_rows) return;
    long long off = (long long)row * DFEAT + lane;
    float x = buf[off];
    float ss = x * x;
    #pragma unroll
    for (int o = 32; o > 0; o >>= 1) ss += __shfl_xor(ss, o, 64);
    float scale = 1.0f / fmaxf(sqrtf(ss), EPS);
    buf[off] = x * scale;
}

extern "C" void kernel_launch(void* const* d_in, const int* in_sizes, int n_in,
                              void* d_out, int out_size, void* d_ws, size_t ws_size,
                              hipStream_t stream) {
    const float* user_feat = (const float*)d_in[0];
    const float* item_feat = (const float*)d_in[1];
    const float* norm_ui   = (const float*)d_in[2];
    const float* norm_iu   = (const float*)d_in[3];
    const int* src_ui = (const int*)d_in[4];
    const int* dst_ui = (const int*)d_in[5];
    const int* src_iu = (const int*)d_in[6];
    const int* dst_iu = (const int*)d_in[7];

    const int n_nodes = in_sizes[0] / DFEAT;   // 100000
    const int n_edges = in_sizes[4];           // 4000000
    const int n_bins  = 2 * n_nodes;           // 200000
    const int nchunks = (n_bins + 255) / 256;  // 782

    // ws layout: cnt[n_bins] | rowptr[n_bins+1] | cursor[n_bins]
    //            | chunksum[nchunks] | chunkoff[nchunks+1] | srcw[2*n_edges]
    auto align256 = [](size_t x) { return (x + 255) & ~(size_t)255; };
    const size_t o_cnt    = 0;
    const size_t o_rowptr = align256(o_cnt + (size_t)n_bins * 4);
    const size_t o_cursor = align256(o_rowptr + ((size_t)n_bins + 1) * 4);
    const size_t o_csum   = align256(o_cursor + (size_t)n_bins * 4);
    const size_t o_coff   = align256(o_csum + (size_t)nchunks * 4);
    const size_t o_srcw   = align256(o_coff + ((size_t)nchunks + 1) * 4);
    const size_t need     = o_srcw + 2ULL * (size_t)n_edges * 4;   // ~34.4 MB

    if (n_nodes <= (1 << 17) && nchunks <= 1024 && ws_size >= need) {
        int* cnt        = (int*)((char*)d_ws + o_cnt);
        int* rowptr     = (int*)((char*)d_ws + o_rowptr);
        int* cursor     = (int*)((char*)d_ws + o_cursor);
        int* chunksum   = (int*)((char*)d_ws + o_csum);
        int* chunkoff   = (int*)((char*)d_ws + o_coff);
        unsigned* srcw  = (unsigned*)((char*)d_ws + o_srcw);

        const long long total = 2LL * n_edges;
        const int tblocks = (int)((total + 255) / 256);

        // 1) zero bin counters (ws is poisoned every call)
        zero_int_kernel<<<(n_bins + 255) / 256, 256, 0, stream>>>(cnt, n_bins);
        // 2) per-bin histogram
        hist_kernel<<<tblocks, 256, 0, stream>>>(dst_ui, dst_iu, cnt,
                                                 n_edges, n_nodes);
        // 3) exclusive scan -> rowptr + cursor
        chunk_sum_kernel<<<nchunks, 256, 0, stream>>>(cnt, chunksum, n_bins);
        chunk_scan_kernel<<<1, 1024, 0, stream>>>(chunksum, chunkoff, nchunks);
        rowptr_kernel<<<nchunks, 256, 0, stream>>>(cnt, chunkoff, rowptr,
                                                   cursor, n_bins);
        // 4) place records at final bin-sorted slots
        place_kernel<<<tblocks, 256, 0, stream>>>(
            src_ui, dst_ui, norm_ui, src_iu, dst_iu, norm_iu,
            cursor, srcw, n_edges, n_nodes);
        // 5) LDS-free CSR gather + fused normalize
        csr_gather_kernel<<<(n_bins + 3) / 4, 256, 0, stream>>>(
            user_feat, item_feat, rowptr, srcw, (float*)d_out, n_nodes);
    } else {
        // Fallback: atomic accumulation directly in d_out (R3 version).
        float* user_acc = (float*)d_out;
        float* item_acc = user_acc + (size_t)n_nodes * DFEAT;
        const int n4 = out_size / 4;
        zero_f32_kernel<<<(n4 + 255) / 256, 256, 0, stream>>>(user_acc, n4);
        const long long total_threads = 2LL * n_edges * DFEAT;
        scatter_edges_kernel<<<(int)((total_threads + 255) / 256), 256, 0, stream>>>(
            user_feat, item_feat, norm_ui, norm_iu,
            src_ui, dst_ui, src_iu, dst_iu, user_acc, item_acc, n_edges);
        const long long norm_threads = (long long)n_bins * DFEAT;
        normalize_rows_kernel<<<(int)((norm_threads + 255) / 256), 256, 0, stream>>>(
            user_acc, n_bins);
    }
}

// Round 2
// 638.051 us; speedup vs baseline: 1.9019x; 1.9019x over previous
//
#include <hip/hip_runtime.h>

#define DFEAT 64
#define EPS 1e-12f
#define BPB 64           // bins per bucket
#define MAXB 3200        // static LDS cap on bucket count (2N/64 = 3125)
#define QPT 4            // quads per thread in partition -> 4096 records/block
#define LSORT_CAP 3264   // max records per bucket (mean 2560 + 27%, ~14 sigma)

// ---------------------------------------------------------------------------
// R9: R7 two-level architecture (bucket partition + in-LDS counting sort +
// register gather), occupancy-fixed.
// R8 post-mortem: exact-CSR place_kernel (8M returning global atomics +
// fully scattered 4B stores over 32MB) ran at 600us, VALU 0.6%, WRITE_SIZE
// 0.48GB = 64B/line per 4B store. Block-local aggregation (R7) keeps the
// active write-set L2-resident -> restored.
// R7 defects fixed here:
//   - gather: BPB 128->64 halves lsort to 13.8KB -> 8 blocks/CU
//     (was 30KB -> 40% occupancy), launch_bounds(256,8).
//   - partition: EPT 64->16 (1954 blocks, ~6/CU vs 2/CU) + int4/float4
//     quad loads in both passes; gather staging phases also quad-loaded.
// ---------------------------------------------------------------------------

__device__ __forceinline__ unsigned pack_src_w(int s, float w) {
    // w uniform [0,1): keep 15 bits (sign-free bf16), round-to-nearest.
    unsigned u = __float_as_uint(w) + 0x8000u;
    return (((u >> 16) & 0x7FFFu) << 17) | (unsigned)s;   // src < 2^17
}
__device__ __forceinline__ int unpack_src(unsigned p) { return (int)(p & 0x1FFFFu); }
__device__ __forceinline__ float unpack_w(unsigned p) {
    return __uint_as_float(((p >> 17) & 0x7FFFu) << 16);
}

__global__ void zero_int_kernel(int* __restrict__ p, int n) {
    int i = blockIdx.x * blockDim.x + threadIdx.x;
    if (i < n) p[i] = 0;
}

// Partition all edges (both directions) into buckets of 64 consecutive bins.
// Bins: [0,N) = item_h destinations (ui edges), [N,2N) = user_h (iu edges).
__global__ __launch_bounds__(256, 6) void partition_kernel(
        const int* __restrict__ src_ui,
        const int* __restrict__ dst_ui,
        const float* __restrict__ norm_ui,
        const int* __restrict__ src_iu,
        const int* __restrict__ dst_iu,
        const float* __restrict__ norm_iu,
        int* __restrict__ cursor,
        unsigned* __restrict__ srcw,
        unsigned char* __restrict__ binlo,
        int n_edges, int n_nodes,
        int nbuckets, int cap) {
    __shared__ int cnt[MAXB];
    __shared__ int basearr[MAXB];
    const int tid = threadIdx.x;
    const long long total = 2LL * n_edges;
    const long long qbase = (long long)blockIdx.x * (256 * QPT);

    for (int c = tid; c < nbuckets; c += 256) cnt[c] = 0;
    __syncthreads();

    // pass 1: per-block bucket histogram (quad dst loads, LDS atomics only)
    for (int k = 0; k < QPT; ++k) {
        long long q = qbase + (long long)k * 256 + tid;
        long long g0 = q << 2;
        if (g0 >= total) continue;
        if (g0 + 3 < total && (g0 + 3 < n_edges || g0 >= n_edges)) {
            const bool iu = (g0 >= n_edges);
            long long e0 = iu ? (g0 - n_edges) : g0;
            int4 d = *reinterpret_cast<const int4*>((iu ? dst_iu : dst_ui) + e0);
            int boff = iu ? n_nodes : 0;
            atomicAdd(&cnt[(d.x + boff) >> 6], 1);
            atomicAdd(&cnt[(d.y + boff) >> 6], 1);
            atomicAdd(&cnt[(d.z + boff) >> 6], 1);
            atomicAdd(&cnt[(d.w + boff) >> 6], 1);
        } else {
            for (long long g = g0; g < g0 + 4 && g < total; ++g) {
                int bin = (g < n_edges) ? dst_ui[g]
                                        : n_nodes + dst_iu[g - n_edges];
                atomicAdd(&cnt[bin >> 6], 1);
            }
        }
    }
    __syncthreads();

    // reserve runs: lane-consecutive global atomics (coalesced lines)
    for (int c = tid; c < nbuckets; c += 256) {
        int n = cnt[c];
        basearr[c] = (n > 0) ? atomicAdd(&cursor[c], n) : 0;
    }
    __syncthreads();
    for (int c = tid; c < nbuckets; c += 256) cnt[c] = 0;
    __syncthreads();

    // pass 2: place records (per-block runs stay L2-resident -> writes combine)
    auto place = [&](int bin, int s, float w) {
        int bu = bin >> 6;
        int r = atomicAdd(&cnt[bu], 1);
        int pos = basearr[bu] + r;
        if (pos < cap) {            // statistically impossible overflow guard
            long long slot = (long long)bu * cap + pos;
            srcw[slot] = pack_src_w(s, w);
            binlo[slot] = (unsigned char)(bin & 63);
        }
    };
    for (int k = 0; k < QPT; ++k) {
        long long q = qbase + (long long)k * 256 + tid;
        long long g0 = q << 2;
        if (g0 >= total) continue;
        if (g0 + 3 < total && (g0 + 3 < n_edges || g0 >= n_edges)) {
            const bool iu = (g0 >= n_edges);
            long long e0 = iu ? (g0 - n_edges) : g0;
            int4 d = *reinterpret_cast<const int4*>((iu ? dst_iu : dst_ui) + e0);
            int4 s = *reinterpret_cast<const int4*>((iu ? src_iu : src_ui) + e0);
            float4 w = *reinterpret_cast<const float4*>((iu ? norm_iu : norm_ui) + e0);
            int boff = iu ? n_nodes : 0;
            place(d.x + boff, s.x, w.x);
            place(d.y + boff, s.y, w.y);
            place(d.z + boff, s.z, w.z);
            place(d.w + boff, s.w, w.w);
        } else {
            for (long long g = g0; g < g0 + 4 && g < total; ++g) {
                int bin, s; float w;
                if (g < n_edges) {
                    bin = dst_ui[g]; s = src_ui[g]; w = norm_ui[g];
                } else {
                    long long e = g - n_edges;
                    bin = n_nodes + dst_iu[e]; s = src_iu[e]; w = norm_iu[e];
                }
                place(bin, s, w);
            }
        }
    }
}

// One block per bucket:
//   1) LDS histogram of the bucket's records by local bin (quad loads)
//   2) wave-0 exclusive scan -> rowptr[65]
//   3) LDS scatter into bin-sorted order (quad staging loads)
//   4) per-row wave gather: 8 independent feature loads per iteration,
//      REGISTER accumulation, fused L2-normalize + coalesced store.
__global__ __launch_bounds__(256, 8) void bucket_sort_gather_kernel(
    const float* __restrict__ user_feat,
    const float* __restrict__ item_feat,
    const int* __restrict__ cursor,
    const unsigned* __restrict__ srcw,
    const unsigned char* __restrict__ binlo,
    float* __restrict__ out, int n_nodes, int cap) {
    __shared__ unsigned lsort[LSORT_CAP];   // 12.75 KB
    __shared__ int cnt[BPB];
    __shared__ int cnt2[BPB];
    __shared__ int rowptr[BPB + 1];
    const int tid = threadIdx.x;
    const int lane = tid & 63;
    const int wid = tid >> 6;            // 0..3
    const int c = blockIdx.x;

    int m = cursor[c];
    if (m > cap) m = cap;
    const long long base = (long long)c * cap;

    if (tid < BPB) { cnt[tid] = 0; cnt2[tid] = 0; }
    __syncthreads();

    // phase 1: histogram (uchar4 coalesced binlo reads, LDS atomics)
    for (int i = tid * 4; i < m; i += 1024) {
        if (i + 3 < m) {
            uchar4 b = *reinterpret_cast<const uchar4*>(binlo + base + i);
            atomicAdd(&cnt[(int)b.x], 1);
            atomicAdd(&cnt[(int)b.y], 1);
            atomicAdd(&cnt[(int)b.z], 1);
            atomicAdd(&cnt[(int)b.w], 1);
        } else {
            for (int k = i; k < m; ++k) atomicAdd(&cnt[(int)binlo[base + k]], 1);
        }
    }
    __syncthreads();

    // phase 2: exclusive scan of 64 bins by wave 0
    if (wid == 0) {
        int v = cnt[lane];
        int s = v;
        #pragma unroll
        for (int off = 1; off < 64; off <<= 1) {
            int y = __shfl_up(s, off, 64);
            if (lane >= off) s += y;
        }
        rowptr[lane] = s - v;
        if (lane == 63) rowptr[BPB] = s;
    }
    __syncthreads();

    // phase 3: scatter records into bin-sorted LDS order (uint4/uchar4 loads)
    for (int i = tid * 4; i < m; i += 1024) {
        if (i + 3 < m) {
            uint4 sv = *reinterpret_cast<const uint4*>(srcw + base + i);
            uchar4 b = *reinterpret_cast<const uchar4*>(binlo + base + i);
            int p0 = rowptr[(int)b.x] + atomicAdd(&cnt2[(int)b.x], 1);
            lsort[p0] = sv.x;
            int p1 = rowptr[(int)b.y] + atomicAdd(&cnt2[(int)b.y], 1);
            lsort[p1] = sv.y;
            int p2 = rowptr[(int)b.z] + atomicAdd(&cnt2[(int)b.z], 1);
            lsort[p2] = sv.z;
            int p3 = rowptr[(int)b.w] + atomicAdd(&cnt2[(int)b.w], 1);
            lsort[p3] = sv.w;
        } else {
            for (int k = i; k < m; ++k) {
                int b = (int)binlo[base + k];
                int pos = rowptr[b] + atomicAdd(&cnt2[b], 1);
                lsort[pos] = srcw[base + k];
            }
        }
    }
    __syncthreads();

    // phase 4: per-row register gather + fused normalize + store
    const int n_bins = 2 * n_nodes;
    for (int r = wid; r < BPB; r += 4) {
        int bin_global = c * BPB + r;
        if (bin_global >= n_bins) break;
        const float* feat = (bin_global < n_nodes) ? user_feat : item_feat;
        int js = rowptr[r];
        int je = rowptr[r + 1];
        float acc = 0.f;
        int j = js;
        for (; j + 8 <= je; j += 8) {
            unsigned s0 = lsort[j + 0];
            unsigned s1 = lsort[j + 1];
            unsigned s2 = lsort[j + 2];
            unsigned s3 = lsort[j + 3];
            unsigned s4 = lsort[j + 4];
            unsigned s5 = lsort[j + 5];
            unsigned s6 = lsort[j + 6];
            unsigned s7 = lsort[j + 7];
            float f0 = feat[(long long)unpack_src(s0) * DFEAT + lane];
            float f1 = feat[(long long)unpack_src(s1) * DFEAT + lane];
            float f2 = feat[(long long)unpack_src(s2) * DFEAT + lane];
            float f3 = feat[(long long)unpack_src(s3) * DFEAT + lane];
            float f4 = feat[(long long)unpack_src(s4) * DFEAT + lane];
            float f5 = feat[(long long)unpack_src(s5) * DFEAT + lane];
            float f6 = feat[(long long)unpack_src(s6) * DFEAT + lane];
            float f7 = feat[(long long)unpack_src(s7) * DFEAT + lane];
            acc += unpack_w(s0) * f0;
            acc += unpack_w(s1) * f1;
            acc += unpack_w(s2) * f2;
            acc += unpack_w(s3) * f3;
            acc += unpack_w(s4) * f4;
            acc += unpack_w(s5) * f5;
            acc += unpack_w(s6) * f6;
            acc += unpack_w(s7) * f7;
        }
        for (; j < je; ++j) {
            unsigned s = lsort[j];
            acc += unpack_w(s) * feat[(long long)unpack_src(s) * DFEAT + lane];
        }
        float ss = acc * acc;
        #pragma unroll
        for (int o = 32; o > 0; o >>= 1) ss += __shfl_xor(ss, o, 64);
        float scale = 1.0f / fmaxf(sqrtf(ss), EPS);
        // out rows [0,N) = user_h <- bins [N,2N); rows [N,2N) = item_h <- bins [0,N)
        int out_row = (bin_global < n_nodes) ? (bin_global + n_nodes)
                                             : (bin_global - n_nodes);
        out[(long long)out_row * DFEAT + lane] = acc * scale;
    }
}

// ---------------------------------------------------------------------------
// Fallback atomic path (proven in R3) if ws_size / shape limits are exceeded.
// ---------------------------------------------------------------------------

__global__ void zero_f32_kernel(float* __restrict__ p, int n4) {
    int i = blockIdx.x * blockDim.x + threadIdx.x;
    if (i < n4) reinterpret_cast<float4*>(p)[i] = make_float4(0.f, 0.f, 0.f, 0.f);
}

__global__ void scatter_edges_kernel(const float* __restrict__ user_feat,
                                     const float* __restrict__ item_feat,
                                     const float* __restrict__ norm_ui,
                                     const float* __restrict__ norm_iu,
                                     const int* __restrict__ src_ui,
                                     const int* __restrict__ dst_ui,
                                     const int* __restrict__ src_iu,
                                     const int* __restrict__ dst_iu,
                                     float* __restrict__ user_acc,
                                     float* __restrict__ item_acc,
                                     int n_edges) {
    long long idx = (long long)blockIdx.x * blockDim.x + threadIdx.x;
    int e = (int)(idx >> 6);
    int d = (int)(idx & 63);
    if (e < n_edges) {
        int s = src_ui[e];
        int t = dst_ui[e];
        atomicAdd(&item_acc[(long long)t * DFEAT + d],
                  norm_ui[e] * user_feat[(long long)s * DFEAT + d]);
    } else {
        e -= n_edges;
        if (e < n_edges) {
            int s = src_iu[e];
            int t = dst_iu[e];
            atomicAdd(&user_acc[(long long)t * DFEAT + d],
                      norm_iu[e] * item_feat[(long long)s * DFEAT + d]);
        }
    }
}

__global__ void normalize_rows_kernel(float* __restrict__ buf, int n_rows) {
    int gid = blockIdx.x * blockDim.x + threadIdx.x;
    int row = gid >> 6;
    int lane = gid & 63;
    if (row >= n_rows) return;
    long long off = (long long)row * DFEAT + lane;
    float x = buf[off];
    float ss = x * x;
    #pragma unroll
    for (int o = 32; o > 0; o >>= 1) ss += __shfl_xor(ss, o, 64);
    float scale = 1.0f / fmaxf(sqrtf(ss), EPS);
    buf[off] = x * scale;
}

extern "C" void kernel_launch(void* const* d_in, const int* in_sizes, int n_in,
                              void* d_out, int out_size, void* d_ws, size_t ws_size,
                              hipStream_t stream) {
    const float* user_feat = (const float*)d_in[0];
    const float* item_feat = (const float*)d_in[1];
    const float* norm_ui   = (const float*)d_in[2];
    const float* norm_iu   = (const float*)d_in[3];
    const int* src_ui = (const int*)d_in[4];
    const int* dst_ui = (const int*)d_in[5];
    const int* src_iu = (const int*)d_in[6];
    const int* dst_iu = (const int*)d_in[7];

    const int n_nodes = in_sizes[0] / DFEAT;   // 100000
    const int n_edges = in_sizes[4];           // 4000000
    const int n_bins  = 2 * n_nodes;
    const int nbuckets = (n_bins + BPB - 1) / BPB;   // 3125

    // ws layout: cursor [nbuckets i32, padded to 256B] | srcw [nbuckets*cap u32]
    //            | binlo [nbuckets*cap u8].  cap multiple of 16; also capped at
    //            LSORT_CAP so the gather's LDS staging always fits.
    const size_t head_bytes = (((size_t)nbuckets * 4) + 255) & ~(size_t)255;
    long long cap_ll = 0;
    if (ws_size > head_bytes) {
        cap_ll = (long long)((ws_size - head_bytes) / ((size_t)nbuckets * 5));
        cap_ll &= ~15LL;
    }
    if (cap_ll > LSORT_CAP) cap_ll = LSORT_CAP;
    const long long mean_per_bucket = 2LL * n_edges / (nbuckets > 0 ? nbuckets : 1);
    const long long cap_needed = mean_per_bucket + mean_per_bucket / 4 + 64;
    const int cap = (int)cap_ll;

    if (nbuckets <= MAXB && n_nodes <= (1 << 17) && cap_ll >= cap_needed) {
        int* cursor = (int*)d_ws;
        unsigned* srcw = (unsigned*)((char*)d_ws + head_bytes);
        unsigned char* binlo = (unsigned char*)((char*)srcw + (size_t)nbuckets * cap * 4);

        // 1) zero bucket cursors (ws is poisoned every call)
        zero_int_kernel<<<(nbuckets + 255) / 256, 256, 0, stream>>>(cursor, nbuckets);
        // 2) partition edges into buckets (LDS aggregation, clustered writes)
        long long total = 2LL * n_edges;
        long long rpb = 256LL * QPT * 4;      // 4096 records per block
        int pblocks = (int)((total + rpb - 1) / rpb);   // 1954
        partition_kernel<<<pblocks, 256, 0, stream>>>(
            src_ui, dst_ui, norm_ui, src_iu, dst_iu, norm_iu,
            cursor, srcw, binlo, n_edges, n_nodes, nbuckets, cap);
        // 3) per-bucket counting sort + per-row register gather + normalize
        bucket_sort_gather_kernel<<<nbuckets, 256, 0, stream>>>(
            user_feat, item_feat, cursor, srcw, binlo,
            (float*)d_out, n_nodes, cap);
    } else {
        // Fallback: atomic accumulation directly in d_out (R3 version).
        float* user_acc = (float*)d_out;
        float* item_acc = user_acc + (size_t)n_nodes * DFEAT;
        const int n4 = out_size / 4;
        zero_f32_kernel<<<(n4 + 255) / 256, 256, 0, stream>>>(user_acc, n4);
        const long long total_threads = 2LL * n_edges * DFEAT;
        scatter_edges_kernel<<<(int)((total_threads + 255) / 256), 256, 0, stream>>>(
            user_feat, item_feat, norm_ui, norm_iu,
            src_ui, dst_ui, src_iu, dst_iu, user_acc, item_acc, n_edges);
        const long long norm_threads = (long long)n_bins * DFEAT;
        normalize_rows_kernel<<<(int)((norm_threads + 255) / 256), 256, 0, stream>>>(
            user_acc, n_bins);
    }
}